// Round 6
// baseline (2401.039 us; speedup 1.0000x reference)
//
#include <hip/hip_runtime.h>
#include <stdint.h>

// ============================================================================
// Encoder (6-layer rel-pos transformer), MI355X. f32 in/out, bf16 internals.
// R11: (1) gemm_bt4 pipelined dbuf resurrected with __launch_bounds__(256,4)
// — R7's 88MB scratch spill was the compiler targeting max-occupancy (VGPR 44)
// absent a min-waves hint; cap at 4 waves/EU gives a 128-VGPR budget, no spill.
// One barrier per K-step, loads issued before MFMA. (2) flash_attn exact VALU
// diet: q pre-scale folds log2e (scores/band/max in exp2 domain -> bare
// v_exp_f32), native bf16 cvt_pk for P-store, exact defer-rescale when no row
// max grows, max-tree reduce.
// ============================================================================

typedef unsigned short u16;
typedef __attribute__((ext_vector_type(8))) __bf16 bf16x8;
typedef __attribute__((ext_vector_type(4))) float f32x4;

#define B_ 8
#define T_ 768
#define C_ 512
#define F_ 2048
#define LOG2E 1.4426950408889634f

__device__ __forceinline__ float b2f(u16 u) {
    union { float f; uint32_t i; } x; x.i = ((uint32_t)u) << 16; return x.f;
}
__device__ __forceinline__ u16 f2b(float f) {
    union { float f; uint32_t i; } x; x.f = f;
    return (u16)((x.i + 0x7fffu + ((x.i >> 16) & 1u)) >> 16);  // RNE
}

// ---------------------------------------------------------------------------
// gemm_bt4: 64x64 block, 256 threads, 4 waves (2x2), each wave 32x32 output.
// Pipelined double-buffer: issue next K-tile loads BEFORE MFMA on current,
// write to other buffer after, ONE barrier per K-step. __launch_bounds__
// (256,4) caps occupancy goal -> 128 VGPR budget -> staged regs stay in VGPRs
// (R7 regression root-caused: no hint => compiler spilled to chase occupancy).
// EPI: 0=bias, 1=bias+relu, 3=bias+scale on cols<512 (QKV fused q*log2e/8).
// ---------------------------------------------------------------------------
template <int EPI>
__global__ __launch_bounds__(256, 4) void gemm_bt4(
    const u16* __restrict__ A, int aStride,
    const u16* __restrict__ Bt, int bStride,
    const float* __restrict__ bias,
    u16* __restrict__ out, int oStride, int K, float epiScale)
{
    const int tid = threadIdx.x;
    const int wave = tid >> 6, lane = tid & 63;
    const int wm = wave & 1, wn = wave >> 1;
    const int quad = lane >> 4, l16 = lane & 15;
    const int m0 = blockIdx.x * 64;
    const int n0 = blockIdx.y * 64;

    __shared__ u16 As[2][64 * 64];
    __shared__ u16 Bs[2][64 * 64];

    const f32x4 vzero = {0.f, 0.f, 0.f, 0.f};
    f32x4 acc[2][2];
#pragma unroll
    for (int i = 0; i < 2; ++i)
#pragma unroll
        for (int j = 0; j < 2; ++j) acc[i][j] = vzero;

    // prologue: stage K-tile 0 into buffer 0 directly
#pragma unroll
    for (int i = 0; i < 2; ++i) {
        int c = tid + i * 256;
        int row = c >> 3, pc = c & 7, lc = pc ^ (row & 7);
        *(uint4*)&As[0][c * 8] =
            *(const uint4*)(A + (long long)(m0 + row) * aStride + lc * 8);
        *(uint4*)&Bs[0][c * 8] =
            *(const uint4*)(Bt + (long long)(n0 + row) * bStride + lc * 8);
    }
    __syncthreads();

    int cb = 0;
    for (int k0 = 0; k0 < K; k0 += 64) {
        uint4 areg[2], breg[2];
        const bool pre = (k0 + 64 < K);
        if (pre) {
#pragma unroll
            for (int i = 0; i < 2; ++i) {
                int c = tid + i * 256;
                int row = c >> 3, pc = c & 7, lc = pc ^ (row & 7);
                areg[i] = *(const uint4*)(A + (long long)(m0 + row) * aStride
                                          + (k0 + 64 + lc * 8));
                breg[i] = *(const uint4*)(Bt + (long long)(n0 + row) * bStride
                                          + (k0 + 64 + lc * 8));
            }
        }
        __builtin_amdgcn_s_setprio(1);
#pragma unroll
        for (int ks = 0; ks < 2; ++ks) {
            bf16x8 af[2], bfr[2];
#pragma unroll
            for (int mi = 0; mi < 2; ++mi) {
                int row = wm * 32 + mi * 16 + l16;
                int pc = ((ks << 2) | quad) ^ (row & 7);
                af[mi] = *(const bf16x8*)&As[cb][row * 64 + pc * 8];
            }
#pragma unroll
            for (int ni = 0; ni < 2; ++ni) {
                int row = wn * 32 + ni * 16 + l16;
                int pc = ((ks << 2) | quad) ^ (row & 7);
                bfr[ni] = *(const bf16x8*)&Bs[cb][row * 64 + pc * 8];
            }
#pragma unroll
            for (int mi = 0; mi < 2; ++mi)
#pragma unroll
                for (int ni = 0; ni < 2; ++ni)
                    acc[mi][ni] = __builtin_amdgcn_mfma_f32_16x16x32_bf16(
                        bfr[ni], af[mi], acc[mi][ni], 0, 0, 0);
        }
        __builtin_amdgcn_s_setprio(0);
        if (pre) {
#pragma unroll
            for (int i = 0; i < 2; ++i) {
                int c = tid + i * 256;
                *(uint4*)&As[cb ^ 1][c * 8] = areg[i];
                *(uint4*)&Bs[cb ^ 1][c * 8] = breg[i];
            }
            __syncthreads();
            cb ^= 1;
        }
    }

#pragma unroll
    for (int mi = 0; mi < 2; ++mi) {
        int row = m0 + wm * 32 + mi * 16 + l16;
#pragma unroll
        for (int ni = 0; ni < 2; ++ni) {
            int colb = n0 + wn * 32 + ni * 16 + quad * 4;
            u16 pk[4];
#pragma unroll
            for (int r = 0; r < 4; ++r) {
                float v = acc[mi][ni][r] + bias[colb + r];
                if (EPI == 1) v = v > 0.f ? v : 0.f;
                if (EPI == 3) { if (colb + r < 512) v *= epiScale; }
                pk[r] = f2b(v);
            }
            uint2 p;
            p.x = (uint32_t)pk[0] | ((uint32_t)pk[1] << 16);
            p.y = (uint32_t)pk[2] | ((uint32_t)pk[3] << 16);
            *(uint2*)(out + (long long)row * oStride + colb) = p;
        }
    }
}

// ---------------------------------------------------------------------------
// bandg[(t*8 + h)*9 + e] = q~[t,h,:] . erk[e,:]  (q pre-scaled by log2e/8 —
// band lands in the same exp2 domain as the QK^T scores automatically)
// ---------------------------------------------------------------------------
__global__ __launch_bounds__(256) void bandg_k(
    const u16* __restrict__ qkv, const float* __restrict__ erk,
    float* __restrict__ bandg)
{
    __shared__ float erkS[576];
    const int tid = threadIdx.x;
    for (int idx = tid; idx < 576; idx += 256) erkS[idx] = erk[idx];
    __syncthreads();
    const int gid = blockIdx.x * 256 + tid;       // 49152
    const int row = gid >> 3, h = gid & 7;
    const u16* q = qkv + (long long)row * 1536 + h * 64;
    float acc[9];
#pragma unroll
    for (int e = 0; e < 9; ++e) acc[e] = 0.f;
#pragma unroll
    for (int c = 0; c < 8; ++c) {
        uint4 d4 = *(const uint4*)(q + c * 8);
        const uint32_t dw[4] = {d4.x, d4.y, d4.z, d4.w};
#pragma unroll
        for (int j = 0; j < 8; ++j) {
            u16 uu = (u16)((dw[j >> 1] >> ((j & 1) * 16)) & 0xffff);
            float qv = b2f(uu);
            int d = c * 8 + j;
#pragma unroll
            for (int e = 0; e < 9; ++e) acc[e] += qv * erkS[e * 64 + d];
        }
    }
    float* o = bandg + (long long)gid * 9;
#pragma unroll
    for (int e = 0; e < 9; ++e) o[e] = acc[e];
}

// ---------------------------------------------------------------------------
// Flash attention, R6 pipeline + R11 VALU diet (exp2 domain; native bf16
// pack; exact defer-rescale). Softmax values bit-identical to exp-domain:
// exp2(s*log2e - m*log2e) == exp(s - m).
// ---------------------------------------------------------------------------
__global__ __launch_bounds__(256) void flash_attn(
    const u16* __restrict__ qkv, const u16* __restrict__ vt,
    const float* __restrict__ mask, const float* __restrict__ bandg,
    const float* __restrict__ erv, u16* __restrict__ outb)
{
    const int tid = threadIdx.x;
    const int w = tid >> 6, lane = tid & 63;
    const int quad = lane >> 4, l16 = lane & 15;
    const int orig = blockIdx.y * 12 + blockIdx.x;
    const int swz = (orig & 7) * 96 + (orig >> 3);
    const int qt = swz % 12, bh = swz / 12;
    const int b = bh >> 3, h = bh & 7;
    const int q0 = qt * 64;

    __shared__ u16 Ql[64 * 64];
    __shared__ u16 Kt[2][64 * 64];
    __shared__ u16 Vt[2][64 * 64];
    __shared__ u16 Pl[4][16 * 64];
    __shared__ float bandk[64][10];
    __shared__ float maskK[2][64];

#pragma unroll
    for (int i = 0; i < 2; ++i) {
        int c = tid + i * 256;
        int r = c >> 3, pc = c & 7, lc = pc ^ (r & 7);
        *(uint4*)&Ql[c * 8] =
            *(const uint4*)(qkv + (long long)(b * T_ + q0 + r) * 1536 + h * 64 + lc * 8);
    }
#pragma unroll
    for (int i = 0; i < 2; ++i) {
        int c = tid + i * 256;
        int r = c >> 3, pc = c & 7, lc = pc ^ (r & 7);
        *(uint4*)&Kt[0][c * 8] =
            *(const uint4*)(qkv + (long long)(b * T_ + r) * 1536 + 512 + h * 64 + lc * 8);
        *(uint4*)&Vt[0][c * 8] =
            *(const uint4*)(vt + ((long long)bh * 64 + r) * T_ + lc * 8);
    }
    if (tid < 64) maskK[0][tid] = mask[b * T_ + tid];
    for (int idx = tid; idx < 576; idx += 256) {
        int r = idx / 9, e = idx - r * 9;
        bandk[r][e] = bandg[((long long)(b * T_ + q0 + r) * 8 + h) * 9 + e];
    }

    const int i_row = q0 + w * 16 + l16;
    const float mi = mask[b * T_ + i_row];
    float m_run = -1e30f, l_run = 0.f;
    const f32x4 vzero = {0.f, 0.f, 0.f, 0.f};
    f32x4 vacc[4] = {vzero, vzero, vzero, vzero};
    float pb[3] = {0.f, 0.f, 0.f};

    __syncthreads();
    bf16x8 qf[2];
#pragma unroll
    for (int ks = 0; ks < 2; ++ks) {
        int r = w * 16 + l16;
        int pc = ((ks << 2) | quad) ^ (r & 7);
        qf[ks] = *(const bf16x8*)&Ql[r * 64 + pc * 8];
    }

    int cbuf = 0;
    for (int kt = 0; kt < 12; ++kt) {
        uint4 kreg[2], vreg[2];
        float mreg = 0.f;
        const bool pre = (kt < 11);
        if (pre) {
            const int ktn = kt + 1;
#pragma unroll
            for (int i = 0; i < 2; ++i) {
                int c = tid + i * 256;
                int r = c >> 3, pc = c & 7, lc = pc ^ (r & 7);
                kreg[i] = *(const uint4*)(qkv + (long long)(b * T_ + ktn * 64 + r) * 1536
                                          + 512 + h * 64 + lc * 8);
                vreg[i] = *(const uint4*)(vt + ((long long)bh * 64 + r) * T_
                                          + ktn * 64 + lc * 8);
            }
            if (tid < 64) mreg = mask[b * T_ + ktn * 64 + tid];
        }

        const float mkv = maskK[cbuf][lane];
        const bool tile_clean = (__ballot(mkv == 0.f) == 0ull);
        const bool fast = tile_clean && (mi != 0.f);
        const bool has_band = (kt * 64 <= q0 + w * 16 + 19) &&
                              (kt * 64 + 67 >= q0 + w * 16);

        f32x4 sacc[4];
#pragma unroll
        for (int ni = 0; ni < 4; ++ni) sacc[ni] = vzero;
        __builtin_amdgcn_s_setprio(1);
#pragma unroll
        for (int ks = 0; ks < 2; ++ks)
#pragma unroll
            for (int ni = 0; ni < 4; ++ni) {
                int r = ni * 16 + l16;
                int pc = ((ks << 2) | quad) ^ (r & 7);
                bf16x8 kf = *(const bf16x8*)&Kt[cbuf][r * 64 + pc * 8];
                sacc[ni] = __builtin_amdgcn_mfma_f32_16x16x32_bf16(kf, qf[ks], sacc[ni], 0, 0, 0);
            }
        __builtin_amdgcn_s_setprio(0);

        if (has_band) {
#pragma unroll
            for (int ni = 0; ni < 4; ++ni)
#pragma unroll
                for (int r = 0; r < 4; ++r) {
                    int jl = ni * 16 + quad * 4 + r;
                    int dlt = kt * 64 + jl - i_row;
                    if (dlt >= -4 && dlt <= 4)
                        sacc[ni][r] += bandk[w * 16 + l16][dlt + 4];
                }
        }
        if (!fast) {
#pragma unroll
            for (int ni = 0; ni < 4; ++ni)
#pragma unroll
                for (int r = 0; r < 4; ++r) {
                    int jl = ni * 16 + quad * 4 + r;
                    if (mi * maskK[cbuf][jl] == 0.f) sacc[ni][r] = -14427.0f;
                }
        }

        // row max: pairwise tree (encourages v_max3 fusion, shorter dep chain)
        float t0, t1, mx;
        {
            float a0 = fmaxf(sacc[0][0], sacc[0][1]), a1 = fmaxf(sacc[0][2], sacc[0][3]);
            float b0 = fmaxf(sacc[1][0], sacc[1][1]), b1 = fmaxf(sacc[1][2], sacc[1][3]);
            float c0 = fmaxf(sacc[2][0], sacc[2][1]), c1 = fmaxf(sacc[2][2], sacc[2][3]);
            float d0 = fmaxf(sacc[3][0], sacc[3][1]), d1 = fmaxf(sacc[3][2], sacc[3][3]);
            t0 = fmaxf(fmaxf(a0, a1), fmaxf(b0, b1));
            t1 = fmaxf(fmaxf(c0, c1), fmaxf(d0, d1));
            mx = fmaxf(t0, t1);
        }
        mx = fmaxf(mx, __shfl_xor(mx, 16));
        mx = fmaxf(mx, __shfl_xor(mx, 32));
        float m_new = fmaxf(m_run, mx);
        // exact defer: if NO row's max grew, every alpha == 1 — skip rescale.
        if (__any(mx > m_run)) {
            float alpha = exp2f(m_run - m_new);
            l_run *= alpha;
#pragma unroll
            for (int ni = 0; ni < 4; ++ni) vacc[ni] = vacc[ni] * alpha;
#pragma unroll
            for (int k = 0; k < 3; ++k) pb[k] *= alpha;
        }
        m_run = m_new;

        // exp2 + native-pack P tile (v_cvt_pk_bf16_f32 via compiler)
        float lsum = 0.f;
#pragma unroll
        for (int ni = 0; ni < 4; ++ni) {
            float u0 = exp2f(sacc[ni][0] - m_new);
            float u1 = exp2f(sacc[ni][1] - m_new);
            float u2 = exp2f(sacc[ni][2] - m_new);
            float u3 = exp2f(sacc[ni][3] - m_new);
            lsum += (u0 + u1) + (u2 + u3);
            union { __bf16 h[2]; uint32_t u; } cA, cB;
            cA.h[0] = (__bf16)u0; cA.h[1] = (__bf16)u1;
            cB.h[0] = (__bf16)u2; cB.h[1] = (__bf16)u3;
            int c0 = ni * 16 + quad * 4;
            int phys = (((c0 >> 3) ^ (l16 & 7)) << 3) + (c0 & 7);
            uint2 p; p.x = cA.u; p.y = cB.u;
            *(uint2*)&Pl[w][l16 * 64 + phys] = p;
        }
        l_run += lsum;

        if (has_band) {
#pragma unroll
            for (int k = 0; k < 3; ++k) {
                int e = quad * 3 + k;
                if (e < 9) {
                    int jl = i_row + e - 4 - kt * 64;
                    if (jl >= 0 && jl < 64) {
                        int phys = (((jl >> 3) ^ (l16 & 7)) << 3) + (jl & 7);
                        pb[k] += b2f(Pl[w][l16 * 64 + phys]);
                    }
                }
            }
        }

        __builtin_amdgcn_s_setprio(1);
#pragma unroll
        for (int ks = 0; ks < 2; ++ks) {
            int pcc = ((ks << 2) | quad) ^ (l16 & 7);
            bf16x8 pf = *(const bf16x8*)&Pl[w][l16 * 64 + pcc * 8];
#pragma unroll
            for (int ni = 0; ni < 4; ++ni) {
                int r = ni * 16 + l16;
                int pc = ((ks << 2) | quad) ^ (r & 7);
                bf16x8 vf = *(const bf16x8*)&Vt[cbuf][r * 64 + pc * 8];
                vacc[ni] = __builtin_amdgcn_mfma_f32_16x16x32_bf16(vf, pf, vacc[ni], 0, 0, 0);
            }
        }
        __builtin_amdgcn_s_setprio(0);

        if (pre) {
#pragma unroll
            for (int i = 0; i < 2; ++i) {
                int c = tid + i * 256;
                *(uint4*)&Kt[cbuf ^ 1][c * 8] = kreg[i];
                *(uint4*)&Vt[cbuf ^ 1][c * 8] = vreg[i];
            }
            if (tid < 64) maskK[cbuf ^ 1][tid] = mreg;
            __syncthreads();
            cbuf ^= 1;
        }
    }

    l_run += __shfl_xor(l_run, 16);
    l_run += __shfl_xor(l_run, 32);
    const float rinv = 1.f / l_run;

    float pband[9];
#pragma unroll
    for (int e = 0; e < 9; ++e) {
        float val = (quad == e / 3) ? pb[e % 3] : 0.f;
        val += __shfl_xor(val, 16);
        val += __shfl_xor(val, 32);
        pband[e] = val * rinv;
    }

    u16* orow = outb + (long long)(b * T_ + i_row) * C_ + h * 64;
#pragma unroll
    for (int ni = 0; ni < 4; ++ni) {
        u16 pk[4];
#pragma unroll
        for (int r = 0; r < 4; ++r) {
            int d = ni * 16 + quad * 4 + r;
            float v = vacc[ni][r] * rinv;
#pragma unroll
            for (int e = 0; e < 9; ++e) v += pband[e] * erv[e * 64 + d];
            pk[r] = f2b(v);
        }
        uint2 p;
        p.x = (uint32_t)pk[0] | ((uint32_t)pk[1] << 16);
        p.y = (uint32_t)pk[2] | ((uint32_t)pk[3] << 16);
        *(uint2*)(orow + ni * 16 + quad * 4) = p;
    }
}

// ---------------------------------------------------------------------------
// One-time weight transposes (f32 -> bf16), batched over layers.
// ---------------------------------------------------------------------------
__global__ void transpose_qkvo(const float* __restrict__ Wq, const float* __restrict__ Wk,
                               const float* __restrict__ Wv, const float* __restrict__ Wo,
                               u16* __restrict__ wqkvT, u16* __restrict__ woT)
{
    __shared__ u16 tile[32][33];
    const int z = blockIdx.z, l = z >> 2, which = z & 3;
    const float* src = (which == 0 ? Wq : which == 1 ? Wk : which == 2 ? Wv : Wo)
                       + (long long)l * 262144;
    u16* dst = (which == 3) ? woT + (long long)l * 262144
                            : wqkvT + (long long)l * 786432 + which * 262144;
    const int r0 = blockIdx.y * 32, c0 = blockIdx.x * 32;
    const int tx = threadIdx.x, ty = threadIdx.y;
#pragma unroll
    for (int i = 0; i < 32; i += 8)
        tile[ty + i][tx] = f2b(src[(long long)(r0 + ty + i) * 512 + (c0 + tx)]);
    __syncthreads();
#pragma unroll
    for (int i = 0; i < 32; i += 8)
        dst[(long long)(c0 + ty + i) * 512 + (r0 + tx)] = tile[tx][ty + i];
}

__global__ void transpose_f2bL(const float* __restrict__ src0, int sStride, long long sLayer,
                               u16* __restrict__ dst0, int dStride, long long dLayer)
{
    __shared__ u16 tile[32][33];
    const int l = blockIdx.z;
    const float* src = src0 + (long long)l * sLayer;
    u16* dst = dst0 + (long long)l * dLayer;
    const int r0 = blockIdx.y * 32, c0 = blockIdx.x * 32;
    const int tx = threadIdx.x, ty = threadIdx.y;
#pragma unroll
    for (int i = 0; i < 32; i += 8)
        tile[ty + i][tx] = f2b(src[(long long)(r0 + ty + i) * sStride + (c0 + tx)]);
    __syncthreads();
#pragma unroll
    for (int i = 0; i < 32; i += 8)
        dst[(long long)(c0 + ty + i) * dStride + (r0 + tx)] = tile[tx][ty + i];
}

__global__ void transpose_b(const u16* __restrict__ src, long long sB1, long long sB2, int sStride,
                            u16* __restrict__ dst, long long dB1, long long dB2, int dStride)
{
    __shared__ u16 tile[32][33];
    const int z = blockIdx.z, zb = z >> 3, zh = z & 7;
    src += (long long)zb * sB1 + (long long)zh * sB2;
    dst += (long long)zb * dB1 + (long long)zh * dB2;
    const int r0 = blockIdx.y * 32, c0 = blockIdx.x * 32;
    const int tx = threadIdx.x, ty = threadIdx.y;
#pragma unroll
    for (int i = 0; i < 32; i += 8)
        tile[ty + i][tx] = src[(long long)(r0 + ty + i) * sStride + (c0 + tx)];
    __syncthreads();
#pragma unroll
    for (int i = 0; i < 32; i += 8)
        dst[(long long)(c0 + ty + i) * dStride + (r0 + tx)] = tile[tx][ty + i];
}

__global__ void concat_bias(const float* __restrict__ bq, const float* __restrict__ bk,
                            const float* __restrict__ bv, float* __restrict__ dst)
{
    int i = blockIdx.x * 256 + threadIdx.x;
    int l = i / 1536, n = i - l * 1536;
    float v = (n < 512) ? bq[l * 512 + n]
             : (n < 1024 ? bk[l * 512 + (n - 512)] : bv[l * 512 + (n - 1024)]);
    dst[i] = v;
}

__global__ void mask_in(const float* __restrict__ x, const float* __restrict__ mask,
                        u16* __restrict__ out)
{
    int i4 = (blockIdx.x * 256 + threadIdx.x) * 4;
    float4 xv = *(const float4*)(x + i4);
    float m = mask[i4 >> 9];
    u16 pk[4] = {f2b(xv.x * m), f2b(xv.y * m), f2b(xv.z * m), f2b(xv.w * m)};
    uint2 p; p.x = (uint32_t)pk[0] | ((uint32_t)pk[1] << 16);
    p.y = (uint32_t)pk[2] | ((uint32_t)pk[3] << 16);
    *(uint2*)(out + i4) = p;
}

__global__ void mask_out(const u16* __restrict__ x, const float* __restrict__ mask,
                         float* __restrict__ out)
{
    int i4 = (blockIdx.x * 256 + threadIdx.x) * 4;
    uint2 p = *(const uint2*)(x + i4);
    float m = mask[i4 >> 9];
    float4 o;
    o.x = b2f((u16)(p.x & 0xffff)) * m;
    o.y = b2f((u16)(p.x >> 16)) * m;
    o.z = b2f((u16)(p.y & 0xffff)) * m;
    o.w = b2f((u16)(p.y >> 16)) * m;
    *(float4*)(out + i4) = o;
}

__global__ __launch_bounds__(256) void add_ln(
    const u16* __restrict__ x, const u16* __restrict__ y,
    const float* __restrict__ sc, const float* __restrict__ bi,
    u16* __restrict__ outx)
{
    const int wave = threadIdx.x >> 6, lane = threadIdx.x & 63;
    const long long r = (long long)blockIdx.x * 4 + wave;
    const u16* xr = x + r * C_;
    const u16* yr = y + r * C_;
    float v[8], s = 0.f;
#pragma unroll
    for (int it = 0; it < 2; ++it) {
        int j0 = it * 256 + lane * 4;
        uint2 px = *(const uint2*)(xr + j0);
        uint2 py = *(const uint2*)(yr + j0);
        v[it * 4 + 0] = b2f((u16)(px.x & 0xffff)) + b2f((u16)(py.x & 0xffff));
        v[it * 4 + 1] = b2f((u16)(px.x >> 16))    + b2f((u16)(py.x >> 16));
        v[it * 4 + 2] = b2f((u16)(px.y & 0xffff)) + b2f((u16)(py.y & 0xffff));
        v[it * 4 + 3] = b2f((u16)(px.y >> 16))    + b2f((u16)(py.y >> 16));
        s += v[it * 4 + 0] + v[it * 4 + 1] + v[it * 4 + 2] + v[it * 4 + 3];
    }
#pragma unroll
    for (int off = 32; off > 0; off >>= 1) s += __shfl_down(s, off);
    s = __shfl(s, 0);
    const float mean = s * (1.f / 512.f);
    float var = 0.f;
#pragma unroll
    for (int l = 0; l < 8; ++l) { float d = v[l] - mean; var += d * d; }
#pragma unroll
    for (int off = 32; off > 0; off >>= 1) var += __shfl_down(var, off);
    var = __shfl(var, 0);
    const float rs = rsqrtf(var * (1.f / 512.f) + 1e-6f);
    u16* orow = outx + r * C_;
#pragma unroll
    for (int it = 0; it < 2; ++it) {
        int j0 = it * 256 + lane * 4;
        float4 s4 = *(const float4*)(sc + j0);
        float4 b4 = *(const float4*)(bi + j0);
        u16 pk[4];
        pk[0] = f2b((v[it * 4 + 0] - mean) * rs * s4.x + b4.x);
        pk[1] = f2b((v[it * 4 + 1] - mean) * rs * s4.y + b4.y);
        pk[2] = f2b((v[it * 4 + 2] - mean) * rs * s4.z + b4.z);
        pk[3] = f2b((v[it * 4 + 3] - mean) * rs * s4.w + b4.w);
        uint2 p; p.x = (uint32_t)pk[0] | ((uint32_t)pk[1] << 16);
        p.y = (uint32_t)pk[2] | ((uint32_t)pk[3] << 16);
        *(uint2*)(orow + j0) = p;
    }
}

// ===========================================================================
extern "C" void kernel_launch(void* const* d_in, const int* in_sizes, int n_in,
                              void* d_out, int out_size, void* d_ws, size_t ws_size,
                              hipStream_t stream)
{
    const float* x    = (const float*)d_in[0];
    const float* mask = (const float*)d_in[1];
    const float* Wq   = (const float*)d_in[2];
    const float* bq   = (const float*)d_in[3];
    const float* Wk   = (const float*)d_in[4];
    const float* bk   = (const float*)d_in[5];
    const float* Wv   = (const float*)d_in[6];
    const float* bv   = (const float*)d_in[7];
    const float* Wo   = (const float*)d_in[8];
    const float* bo   = (const float*)d_in[9];
    const float* erk  = (const float*)d_in[10];
    const float* erv  = (const float*)d_in[11];
    const float* ln1s = (const float*)d_in[12];
    const float* ln1b = (const float*)d_in[13];
    const float* W1   = (const float*)d_in[14];
    const float* b1   = (const float*)d_in[15];
    const float* W2   = (const float*)d_in[16];
    const float* b2   = (const float*)d_in[17];
    const float* ln2s = (const float*)d_in[18];
    const float* ln2b = (const float*)d_in[19];
    float* out = (float*)d_out;
    u16* ws  = (u16*)d_ws;

    const long long CF = 512LL * 2048;
    const int M = B_ * T_;  // 6144

    // ws layout (u16 units). Total 51,234,816 u16 = 102.5 MB (<121.7 MB proven).
    u16* wqkvT   = ws;                      // [6][1536][512]
    u16* woT     = ws + 4718592;            // [6][512][512]
    u16* w1T     = ws + 6291456;            // [6][2048][512]
    u16* w2T     = ws + 12582912;           // [6][512][2048]
    float* bqkv  = (float*)(ws + 18874368); // [6][1536] f32
    u16* xb      = ws + 18892800;           // [M][512]
    u16* qkvb    = ws + 22038528;           // [M][1536]
    u16* vtb     = ws + 31475712;           // [64][64][768]; aliased as yb
    u16* attnb   = ws + 34621440;           // [M][512]
    u16* scr     = ws + 37767168;           // h1 [M][2048]
    float* bandg = (float*)(ws + 50350080); // [M][8][9] f32
    u16* yb      = vtb;

    const dim3 tb(32, 8);

    // --- one-time prologue ---
    transpose_qkvo<<<dim3(16, 16, 24), tb, 0, stream>>>(Wq, Wk, Wv, Wo, wqkvT, woT);
    transpose_f2bL<<<dim3(64, 16, 6), tb, 0, stream>>>(W1, 2048, CF, w1T, 512, 1048576);
    transpose_f2bL<<<dim3(16, 64, 6), tb, 0, stream>>>(W2, 512,  CF, w2T, 2048, 1048576);
    concat_bias<<<36, 256, 0, stream>>>(bq, bk, bv, bqkv);
    mask_in<<<(M * 512) / 1024, 256, 0, stream>>>(x, mask, xb);

    for (int l = 0; l < 6; ++l) {
        // QKV: [6144,512] @ [1536,512]^T; q *= log2e/8 in epilogue (cols<512)
        // -> scores & band are in exp2 domain; softmax uses bare v_exp_f32.
        gemm_bt4<3><<<dim3(96, 24), 256, 0, stream>>>(
            xb, 512, wqkvT + (long long)l * 786432, 512, bqkv + l * 1536,
            qkvb, 1536, 512, 0.125f * LOG2E);
        // bandk table for this layer
        bandg_k<<<192, 256, 0, stream>>>(qkvb, erk + l * 576, bandg);
        // V^T per head: [64][768]
        transpose_b<<<dim3(2, 24, 64), tb, 0, stream>>>(
            qkvb + 1024, 768LL * 1536, 64, 1536,
            vtb, 8LL * 64 * 768, 64LL * 768, 768);
        // fused attention -> attnb
        flash_attn<<<dim3(12, 64), 256, 0, stream>>>(
            qkvb, vtb, mask, bandg, erv + l * 576, attnb);
        // O projection -> yb (=vtb, dead now)
        gemm_bt4<0><<<dim3(96, 8), 256, 0, stream>>>(
            attnb, 512, woT + (long long)l * 262144, 512, bo + l * 512,
            yb, 512, 512, 0.f);
        add_ln<<<1536, 256, 0, stream>>>(xb, yb, ln1s + l * 512, ln1b + l * 512, xb);
        // FFN1 (relu fused)
        gemm_bt4<1><<<dim3(96, 32), 256, 0, stream>>>(
            xb, 512, w1T + (long long)l * 1048576, 512, b1 + l * 2048,
            scr, 2048, 512, 0.f);
        // FFN2
        gemm_bt4<0><<<dim3(96, 8), 256, 0, stream>>>(
            scr, 2048, w2T + (long long)l * 1048576, 2048, b2 + l * 512,
            yb, 512, 2048, 0.f);
        add_ln<<<1536, 256, 0, stream>>>(xb, yb, ln2s + l * 512, ln2b + l * 512, xb);
    }

    mask_out<<<(M * 512) / 1024, 256, 0, stream>>>(xb, mask, out);
}

// Round 7
// 1066.909 us; speedup vs baseline: 2.2505x; 2.2505x over previous
//
#include <hip/hip_runtime.h>
#include <stdint.h>

// ============================================================================
// Encoder (6-layer rel-pos transformer), MI355X. f32 in/out, bf16 internals.
// R12: gemm_bt4 strictly reverted to the R10-verified two-barrier body —
// the pipelined reg-staging spills unconditionally in this kernel (R7 and
// R11 both: VGPR 44, ~84 MB scratch, with AND without launch_bounds hint);
// do not retry without disasm. flash_attn keeps the R11 exact VALU diet
// (exp2 domain via q-prescale, native bf16 cvt_pk P-store, exact
// defer-rescale, max-tree). One variable changed vs R10 => clean A/B of the
// flash diet.
// ============================================================================

typedef unsigned short u16;
typedef __attribute__((ext_vector_type(8))) __bf16 bf16x8;
typedef __attribute__((ext_vector_type(4))) float f32x4;

#define B_ 8
#define T_ 768
#define C_ 512
#define F_ 2048
#define LOG2E 1.4426950408889634f

__device__ __forceinline__ float b2f(u16 u) {
    union { float f; uint32_t i; } x; x.i = ((uint32_t)u) << 16; return x.f;
}
__device__ __forceinline__ u16 f2b(float f) {
    union { float f; uint32_t i; } x; x.f = f;
    return (u16)((x.i + 0x7fffu + ((x.i >> 16) & 1u)) >> 16);  // RNE
}

// ---------------------------------------------------------------------------
// gemm_bt4 (R10-verified): 64x64 block, 256 threads, 4 waves (2x2), wave =
// 32x32 output. Same-iteration uint4 global->LDS staging, two barriers per
// K-step, setprio around MFMA. VGPR 28, no spill — proven. EPI: 0=bias,
// 1=bias+relu, 3=bias+scale on cols<512 (QKV fused q*log2e/8).
// ---------------------------------------------------------------------------
template <int EPI>
__global__ __launch_bounds__(256) void gemm_bt4(
    const u16* __restrict__ A, int aStride,
    const u16* __restrict__ Bt, int bStride,
    const float* __restrict__ bias,
    u16* __restrict__ out, int oStride, int K, float epiScale)
{
    const int tid = threadIdx.x;
    const int wave = tid >> 6, lane = tid & 63;
    const int wm = wave & 1, wn = wave >> 1;
    const int quad = lane >> 4, l16 = lane & 15;
    const int m0 = blockIdx.x * 64;
    const int n0 = blockIdx.y * 64;

    __shared__ u16 As[64 * 64];
    __shared__ u16 Bs[64 * 64];

    const f32x4 vzero = {0.f, 0.f, 0.f, 0.f};
    f32x4 acc[2][2];
#pragma unroll
    for (int i = 0; i < 2; ++i)
#pragma unroll
        for (int j = 0; j < 2; ++j) acc[i][j] = vzero;

    for (int k0 = 0; k0 < K; k0 += 64) {
#pragma unroll
        for (int i = 0; i < 2; ++i) {
            int c = tid + i * 256;
            int row = c >> 3, pc = c & 7, lc = pc ^ (row & 7);
            *(uint4*)&As[c * 8] =
                *(const uint4*)(A + (long long)(m0 + row) * aStride + (k0 + lc * 8));
            *(uint4*)&Bs[c * 8] =
                *(const uint4*)(Bt + (long long)(n0 + row) * bStride + (k0 + lc * 8));
        }
        __syncthreads();
        __builtin_amdgcn_s_setprio(1);
#pragma unroll
        for (int ks = 0; ks < 2; ++ks) {
            bf16x8 af[2], bfr[2];
#pragma unroll
            for (int mi = 0; mi < 2; ++mi) {
                int row = wm * 32 + mi * 16 + l16;
                int pc = ((ks << 2) | quad) ^ (row & 7);
                af[mi] = *(const bf16x8*)&As[row * 64 + pc * 8];
            }
#pragma unroll
            for (int ni = 0; ni < 2; ++ni) {
                int row = wn * 32 + ni * 16 + l16;
                int pc = ((ks << 2) | quad) ^ (row & 7);
                bfr[ni] = *(const bf16x8*)&Bs[row * 64 + pc * 8];
            }
#pragma unroll
            for (int mi = 0; mi < 2; ++mi)
#pragma unroll
                for (int ni = 0; ni < 2; ++ni)
                    acc[mi][ni] = __builtin_amdgcn_mfma_f32_16x16x32_bf16(
                        bfr[ni], af[mi], acc[mi][ni], 0, 0, 0);
        }
        __builtin_amdgcn_s_setprio(0);
        __syncthreads();
    }

#pragma unroll
    for (int mi = 0; mi < 2; ++mi) {
        int row = m0 + wm * 32 + mi * 16 + l16;
#pragma unroll
        for (int ni = 0; ni < 2; ++ni) {
            int colb = n0 + wn * 32 + ni * 16 + quad * 4;
            u16 pk[4];
#pragma unroll
            for (int r = 0; r < 4; ++r) {
                float v = acc[mi][ni][r] + bias[colb + r];
                if (EPI == 1) v = v > 0.f ? v : 0.f;
                if (EPI == 3) { if (colb + r < 512) v *= epiScale; }
                pk[r] = f2b(v);
            }
            uint2 p;
            p.x = (uint32_t)pk[0] | ((uint32_t)pk[1] << 16);
            p.y = (uint32_t)pk[2] | ((uint32_t)pk[3] << 16);
            *(uint2*)(out + (long long)row * oStride + colb) = p;
        }
    }
}

// ---------------------------------------------------------------------------
// bandg[(t*8 + h)*9 + e] = q~[t,h,:] . erk[e,:]  (q pre-scaled by log2e/8 —
// band lands in the same exp2 domain as the QK^T scores automatically)
// ---------------------------------------------------------------------------
__global__ __launch_bounds__(256) void bandg_k(
    const u16* __restrict__ qkv, const float* __restrict__ erk,
    float* __restrict__ bandg)
{
    __shared__ float erkS[576];
    const int tid = threadIdx.x;
    for (int idx = tid; idx < 576; idx += 256) erkS[idx] = erk[idx];
    __syncthreads();
    const int gid = blockIdx.x * 256 + tid;       // 49152
    const int row = gid >> 3, h = gid & 7;
    const u16* q = qkv + (long long)row * 1536 + h * 64;
    float acc[9];
#pragma unroll
    for (int e = 0; e < 9; ++e) acc[e] = 0.f;
#pragma unroll
    for (int c = 0; c < 8; ++c) {
        uint4 d4 = *(const uint4*)(q + c * 8);
        const uint32_t dw[4] = {d4.x, d4.y, d4.z, d4.w};
#pragma unroll
        for (int j = 0; j < 8; ++j) {
            u16 uu = (u16)((dw[j >> 1] >> ((j & 1) * 16)) & 0xffff);
            float qv = b2f(uu);
            int d = c * 8 + j;
#pragma unroll
            for (int e = 0; e < 9; ++e) acc[e] += qv * erkS[e * 64 + d];
        }
    }
    float* o = bandg + (long long)gid * 9;
#pragma unroll
    for (int e = 0; e < 9; ++e) o[e] = acc[e];
}

// ---------------------------------------------------------------------------
// Flash attention, R6 pipeline + R11 VALU diet (exp2 domain; native bf16
// pack; exact defer-rescale). exp2(s*log2e - m*log2e) == exp(s - m).
// ---------------------------------------------------------------------------
__global__ __launch_bounds__(256) void flash_attn(
    const u16* __restrict__ qkv, const u16* __restrict__ vt,
    const float* __restrict__ mask, const float* __restrict__ bandg,
    const float* __restrict__ erv, u16* __restrict__ outb)
{
    const int tid = threadIdx.x;
    const int w = tid >> 6, lane = tid & 63;
    const int quad = lane >> 4, l16 = lane & 15;
    const int orig = blockIdx.y * 12 + blockIdx.x;
    const int swz = (orig & 7) * 96 + (orig >> 3);
    const int qt = swz % 12, bh = swz / 12;
    const int b = bh >> 3, h = bh & 7;
    const int q0 = qt * 64;

    __shared__ u16 Ql[64 * 64];
    __shared__ u16 Kt[2][64 * 64];
    __shared__ u16 Vt[2][64 * 64];
    __shared__ u16 Pl[4][16 * 64];
    __shared__ float bandk[64][10];
    __shared__ float maskK[2][64];

#pragma unroll
    for (int i = 0; i < 2; ++i) {
        int c = tid + i * 256;
        int r = c >> 3, pc = c & 7, lc = pc ^ (r & 7);
        *(uint4*)&Ql[c * 8] =
            *(const uint4*)(qkv + (long long)(b * T_ + q0 + r) * 1536 + h * 64 + lc * 8);
    }
#pragma unroll
    for (int i = 0; i < 2; ++i) {
        int c = tid + i * 256;
        int r = c >> 3, pc = c & 7, lc = pc ^ (r & 7);
        *(uint4*)&Kt[0][c * 8] =
            *(const uint4*)(qkv + (long long)(b * T_ + r) * 1536 + 512 + h * 64 + lc * 8);
        *(uint4*)&Vt[0][c * 8] =
            *(const uint4*)(vt + ((long long)bh * 64 + r) * T_ + lc * 8);
    }
    if (tid < 64) maskK[0][tid] = mask[b * T_ + tid];
    for (int idx = tid; idx < 576; idx += 256) {
        int r = idx / 9, e = idx - r * 9;
        bandk[r][e] = bandg[((long long)(b * T_ + q0 + r) * 8 + h) * 9 + e];
    }

    const int i_row = q0 + w * 16 + l16;
    const float mi = mask[b * T_ + i_row];
    float m_run = -1e30f, l_run = 0.f;
    const f32x4 vzero = {0.f, 0.f, 0.f, 0.f};
    f32x4 vacc[4] = {vzero, vzero, vzero, vzero};
    float pb[3] = {0.f, 0.f, 0.f};

    __syncthreads();
    bf16x8 qf[2];
#pragma unroll
    for (int ks = 0; ks < 2; ++ks) {
        int r = w * 16 + l16;
        int pc = ((ks << 2) | quad) ^ (r & 7);
        qf[ks] = *(const bf16x8*)&Ql[r * 64 + pc * 8];
    }

    int cbuf = 0;
    for (int kt = 0; kt < 12; ++kt) {
        uint4 kreg[2], vreg[2];
        float mreg = 0.f;
        const bool pre = (kt < 11);
        if (pre) {
            const int ktn = kt + 1;
#pragma unroll
            for (int i = 0; i < 2; ++i) {
                int c = tid + i * 256;
                int r = c >> 3, pc = c & 7, lc = pc ^ (r & 7);
                kreg[i] = *(const uint4*)(qkv + (long long)(b * T_ + ktn * 64 + r) * 1536
                                          + 512 + h * 64 + lc * 8);
                vreg[i] = *(const uint4*)(vt + ((long long)bh * 64 + r) * T_
                                          + ktn * 64 + lc * 8);
            }
            if (tid < 64) mreg = mask[b * T_ + ktn * 64 + tid];
        }

        const float mkv = maskK[cbuf][lane];
        const bool tile_clean = (__ballot(mkv == 0.f) == 0ull);
        const bool fast = tile_clean && (mi != 0.f);
        const bool has_band = (kt * 64 <= q0 + w * 16 + 19) &&
                              (kt * 64 + 67 >= q0 + w * 16);

        f32x4 sacc[4];
#pragma unroll
        for (int ni = 0; ni < 4; ++ni) sacc[ni] = vzero;
        __builtin_amdgcn_s_setprio(1);
#pragma unroll
        for (int ks = 0; ks < 2; ++ks)
#pragma unroll
            for (int ni = 0; ni < 4; ++ni) {
                int r = ni * 16 + l16;
                int pc = ((ks << 2) | quad) ^ (r & 7);
                bf16x8 kf = *(const bf16x8*)&Kt[cbuf][r * 64 + pc * 8];
                sacc[ni] = __builtin_amdgcn_mfma_f32_16x16x32_bf16(kf, qf[ks], sacc[ni], 0, 0, 0);
            }
        __builtin_amdgcn_s_setprio(0);

        if (has_band) {
#pragma unroll
            for (int ni = 0; ni < 4; ++ni)
#pragma unroll
                for (int r = 0; r < 4; ++r) {
                    int jl = ni * 16 + quad * 4 + r;
                    int dlt = kt * 64 + jl - i_row;
                    if (dlt >= -4 && dlt <= 4)
                        sacc[ni][r] += bandk[w * 16 + l16][dlt + 4];
                }
        }
        if (!fast) {
#pragma unroll
            for (int ni = 0; ni < 4; ++ni)
#pragma unroll
                for (int r = 0; r < 4; ++r) {
                    int jl = ni * 16 + quad * 4 + r;
                    if (mi * maskK[cbuf][jl] == 0.f) sacc[ni][r] = -14427.0f;
                }
        }

        // row max: pairwise tree
        float mx;
        {
            float a0 = fmaxf(sacc[0][0], sacc[0][1]), a1 = fmaxf(sacc[0][2], sacc[0][3]);
            float b0 = fmaxf(sacc[1][0], sacc[1][1]), b1 = fmaxf(sacc[1][2], sacc[1][3]);
            float c0 = fmaxf(sacc[2][0], sacc[2][1]), c1 = fmaxf(sacc[2][2], sacc[2][3]);
            float d0 = fmaxf(sacc[3][0], sacc[3][1]), d1 = fmaxf(sacc[3][2], sacc[3][3]);
            float t0 = fmaxf(fmaxf(a0, a1), fmaxf(b0, b1));
            float t1 = fmaxf(fmaxf(c0, c1), fmaxf(d0, d1));
            mx = fmaxf(t0, t1);
        }
        mx = fmaxf(mx, __shfl_xor(mx, 16));
        mx = fmaxf(mx, __shfl_xor(mx, 32));
        float m_new = fmaxf(m_run, mx);
        // exact defer: if NO row's max grew, every alpha == 1 — skip rescale.
        if (__any(mx > m_run)) {
            float alpha = exp2f(m_run - m_new);
            l_run *= alpha;
#pragma unroll
            for (int ni = 0; ni < 4; ++ni) vacc[ni] = vacc[ni] * alpha;
#pragma unroll
            for (int k = 0; k < 3; ++k) pb[k] *= alpha;
        }
        m_run = m_new;

        // exp2 + native-pack P tile (v_cvt_pk_bf16_f32 via compiler)
        float lsum = 0.f;
#pragma unroll
        for (int ni = 0; ni < 4; ++ni) {
            float u0 = exp2f(sacc[ni][0] - m_new);
            float u1 = exp2f(sacc[ni][1] - m_new);
            float u2 = exp2f(sacc[ni][2] - m_new);
            float u3 = exp2f(sacc[ni][3] - m_new);
            lsum += (u0 + u1) + (u2 + u3);
            union { __bf16 h[2]; uint32_t u; } cA, cB;
            cA.h[0] = (__bf16)u0; cA.h[1] = (__bf16)u1;
            cB.h[0] = (__bf16)u2; cB.h[1] = (__bf16)u3;
            int c0 = ni * 16 + quad * 4;
            int phys = (((c0 >> 3) ^ (l16 & 7)) << 3) + (c0 & 7);
            uint2 p; p.x = cA.u; p.y = cB.u;
            *(uint2*)&Pl[w][l16 * 64 + phys] = p;
        }
        l_run += lsum;

        if (has_band) {
#pragma unroll
            for (int k = 0; k < 3; ++k) {
                int e = quad * 3 + k;
                if (e < 9) {
                    int jl = i_row + e - 4 - kt * 64;
                    if (jl >= 0 && jl < 64) {
                        int phys = (((jl >> 3) ^ (l16 & 7)) << 3) + (jl & 7);
                        pb[k] += b2f(Pl[w][l16 * 64 + phys]);
                    }
                }
            }
        }

        __builtin_amdgcn_s_setprio(1);
#pragma unroll
        for (int ks = 0; ks < 2; ++ks) {
            int pcc = ((ks << 2) | quad) ^ (l16 & 7);
            bf16x8 pf = *(const bf16x8*)&Pl[w][l16 * 64 + pcc * 8];
#pragma unroll
            for (int ni = 0; ni < 4; ++ni) {
                int r = ni * 16 + l16;
                int pc = ((ks << 2) | quad) ^ (r & 7);
                bf16x8 vf = *(const bf16x8*)&Vt[cbuf][r * 64 + pc * 8];
                vacc[ni] = __builtin_amdgcn_mfma_f32_16x16x32_bf16(vf, pf, vacc[ni], 0, 0, 0);
            }
        }
        __builtin_amdgcn_s_setprio(0);

        if (pre) {
#pragma unroll
            for (int i = 0; i < 2; ++i) {
                int c = tid + i * 256;
                *(uint4*)&Kt[cbuf ^ 1][c * 8] = kreg[i];
                *(uint4*)&Vt[cbuf ^ 1][c * 8] = vreg[i];
            }
            if (tid < 64) maskK[cbuf ^ 1][tid] = mreg;
            __syncthreads();
            cbuf ^= 1;
        }
    }

    l_run += __shfl_xor(l_run, 16);
    l_run += __shfl_xor(l_run, 32);
    const float rinv = 1.f / l_run;

    float pband[9];
#pragma unroll
    for (int e = 0; e < 9; ++e) {
        float val = (quad == e / 3) ? pb[e % 3] : 0.f;
        val += __shfl_xor(val, 16);
        val += __shfl_xor(val, 32);
        pband[e] = val * rinv;
    }

    u16* orow = outb + (long long)(b * T_ + i_row) * C_ + h * 64;
#pragma unroll
    for (int ni = 0; ni < 4; ++ni) {
        u16 pk[4];
#pragma unroll
        for (int r = 0; r < 4; ++r) {
            int d = ni * 16 + quad * 4 + r;
            float v = vacc[ni][r] * rinv;
#pragma unroll
            for (int e = 0; e < 9; ++e) v += pband[e] * erv[e * 64 + d];
            pk[r] = f2b(v);
        }
        uint2 p;
        p.x = (uint32_t)pk[0] | ((uint32_t)pk[1] << 16);
        p.y = (uint32_t)pk[2] | ((uint32_t)pk[3] << 16);
        *(uint2*)(orow + ni * 16 + quad * 4) = p;
    }
}

// ---------------------------------------------------------------------------
// One-time weight transposes (f32 -> bf16), batched over layers.
// ---------------------------------------------------------------------------
__global__ void transpose_qkvo(const float* __restrict__ Wq, const float* __restrict__ Wk,
                               const float* __restrict__ Wv, const float* __restrict__ Wo,
                               u16* __restrict__ wqkvT, u16* __restrict__ woT)
{
    __shared__ u16 tile[32][33];
    const int z = blockIdx.z, l = z >> 2, which = z & 3;
    const float* src = (which == 0 ? Wq : which == 1 ? Wk : which == 2 ? Wv : Wo)
                       + (long long)l * 262144;
    u16* dst = (which == 3) ? woT + (long long)l * 262144
                            : wqkvT + (long long)l * 786432 + which * 262144;
    const int r0 = blockIdx.y * 32, c0 = blockIdx.x * 32;
    const int tx = threadIdx.x, ty = threadIdx.y;
#pragma unroll
    for (int i = 0; i < 32; i += 8)
        tile[ty + i][tx] = f2b(src[(long long)(r0 + ty + i) * 512 + (c0 + tx)]);
    __syncthreads();
#pragma unroll
    for (int i = 0; i < 32; i += 8)
        dst[(long long)(c0 + ty + i) * 512 + (r0 + tx)] = tile[tx][ty + i];
}

__global__ void transpose_f2bL(const float* __restrict__ src0, int sStride, long long sLayer,
                               u16* __restrict__ dst0, int dStride, long long dLayer)
{
    __shared__ u16 tile[32][33];
    const int l = blockIdx.z;
    const float* src = src0 + (long long)l * sLayer;
    u16* dst = dst0 + (long long)l * dLayer;
    const int r0 = blockIdx.y * 32, c0 = blockIdx.x * 32;
    const int tx = threadIdx.x, ty = threadIdx.y;
#pragma unroll
    for (int i = 0; i < 32; i += 8)
        tile[ty + i][tx] = f2b(src[(long long)(r0 + ty + i) * sStride + (c0 + tx)]);
    __syncthreads();
#pragma unroll
    for (int i = 0; i < 32; i += 8)
        dst[(long long)(c0 + ty + i) * dStride + (r0 + tx)] = tile[tx][ty + i];
}

__global__ void transpose_b(const u16* __restrict__ src, long long sB1, long long sB2, int sStride,
                            u16* __restrict__ dst, long long dB1, long long dB2, int dStride)
{
    __shared__ u16 tile[32][33];
    const int z = blockIdx.z, zb = z >> 3, zh = z & 7;
    src += (long long)zb * sB1 + (long long)zh * sB2;
    dst += (long long)zb * dB1 + (long long)zh * dB2;
    const int r0 = blockIdx.y * 32, c0 = blockIdx.x * 32;
    const int tx = threadIdx.x, ty = threadIdx.y;
#pragma unroll
    for (int i = 0; i < 32; i += 8)
        tile[ty + i][tx] = src[(long long)(r0 + ty + i) * sStride + (c0 + tx)];
    __syncthreads();
#pragma unroll
    for (int i = 0; i < 32; i += 8)
        dst[(long long)(c0 + ty + i) * dStride + (r0 + tx)] = tile[tx][ty + i];
}

__global__ void concat_bias(const float* __restrict__ bq, const float* __restrict__ bk,
                            const float* __restrict__ bv, float* __restrict__ dst)
{
    int i = blockIdx.x * 256 + threadIdx.x;
    int l = i / 1536, n = i - l * 1536;
    float v = (n < 512) ? bq[l * 512 + n]
             : (n < 1024 ? bk[l * 512 + (n - 512)] : bv[l * 512 + (n - 1024)]);
    dst[i] = v;
}

__global__ void mask_in(const float* __restrict__ x, const float* __restrict__ mask,
                        u16* __restrict__ out)
{
    int i4 = (blockIdx.x * 256 + threadIdx.x) * 4;
    float4 xv = *(const float4*)(x + i4);
    float m = mask[i4 >> 9];
    u16 pk[4] = {f2b(xv.x * m), f2b(xv.y * m), f2b(xv.z * m), f2b(xv.w * m)};
    uint2 p; p.x = (uint32_t)pk[0] | ((uint32_t)pk[1] << 16);
    p.y = (uint32_t)pk[2] | ((uint32_t)pk[3] << 16);
    *(uint2*)(out + i4) = p;
}

__global__ void mask_out(const u16* __restrict__ x, const float* __restrict__ mask,
                         float* __restrict__ out)
{
    int i4 = (blockIdx.x * 256 + threadIdx.x) * 4;
    uint2 p = *(const uint2*)(x + i4);
    float m = mask[i4 >> 9];
    float4 o;
    o.x = b2f((u16)(p.x & 0xffff)) * m;
    o.y = b2f((u16)(p.x >> 16)) * m;
    o.z = b2f((u16)(p.y & 0xffff)) * m;
    o.w = b2f((u16)(p.y >> 16)) * m;
    *(float4*)(out + i4) = o;
}

__global__ __launch_bounds__(256) void add_ln(
    const u16* __restrict__ x, const u16* __restrict__ y,
    const float* __restrict__ sc, const float* __restrict__ bi,
    u16* __restrict__ outx)
{
    const int wave = threadIdx.x >> 6, lane = threadIdx.x & 63;
    const long long r = (long long)blockIdx.x * 4 + wave;
    const u16* xr = x + r * C_;
    const u16* yr = y + r * C_;
    float v[8], s = 0.f;
#pragma unroll
    for (int it = 0; it < 2; ++it) {
        int j0 = it * 256 + lane * 4;
        uint2 px = *(const uint2*)(xr + j0);
        uint2 py = *(const uint2*)(yr + j0);
        v[it * 4 + 0] = b2f((u16)(px.x & 0xffff)) + b2f((u16)(py.x & 0xffff));
        v[it * 4 + 1] = b2f((u16)(px.x >> 16))    + b2f((u16)(py.x >> 16));
        v[it * 4 + 2] = b2f((u16)(px.y & 0xffff)) + b2f((u16)(py.y & 0xffff));
        v[it * 4 + 3] = b2f((u16)(px.y >> 16))    + b2f((u16)(py.y >> 16));
        s += v[it * 4 + 0] + v[it * 4 + 1] + v[it * 4 + 2] + v[it * 4 + 3];
    }
#pragma unroll
    for (int off = 32; off > 0; off >>= 1) s += __shfl_down(s, off);
    s = __shfl(s, 0);
    const float mean = s * (1.f / 512.f);
    float var = 0.f;
#pragma unroll
    for (int l = 0; l < 8; ++l) { float d = v[l] - mean; var += d * d; }
#pragma unroll
    for (int off = 32; off > 0; off >>= 1) var += __shfl_down(var, off);
    var = __shfl(var, 0);
    const float rs = rsqrtf(var * (1.f / 512.f) + 1e-6f);
    u16* orow = outx + r * C_;
#pragma unroll
    for (int it = 0; it < 2; ++it) {
        int j0 = it * 256 + lane * 4;
        float4 s4 = *(const float4*)(sc + j0);
        float4 b4 = *(const float4*)(bi + j0);
        u16 pk[4];
        pk[0] = f2b((v[it * 4 + 0] - mean) * rs * s4.x + b4.x);
        pk[1] = f2b((v[it * 4 + 1] - mean) * rs * s4.y + b4.y);
        pk[2] = f2b((v[it * 4 + 2] - mean) * rs * s4.z + b4.z);
        pk[3] = f2b((v[it * 4 + 3] - mean) * rs * s4.w + b4.w);
        uint2 p; p.x = (uint32_t)pk[0] | ((uint32_t)pk[1] << 16);
        p.y = (uint32_t)pk[2] | ((uint32_t)pk[3] << 16);
        *(uint2*)(orow + j0) = p;
    }
}

// ===========================================================================
extern "C" void kernel_launch(void* const* d_in, const int* in_sizes, int n_in,
                              void* d_out, int out_size, void* d_ws, size_t ws_size,
                              hipStream_t stream)
{
    const float* x    = (const float*)d_in[0];
    const float* mask = (const float*)d_in[1];
    const float* Wq   = (const float*)d_in[2];
    const float* bq   = (const float*)d_in[3];
    const float* Wk   = (const float*)d_in[4];
    const float* bk   = (const float*)d_in[5];
    const float* Wv   = (const float*)d_in[6];
    const float* bv   = (const float*)d_in[7];
    const float* Wo   = (const float*)d_in[8];
    const float* bo   = (const float*)d_in[9];
    const float* erk  = (const float*)d_in[10];
    const float* erv  = (const float*)d_in[11];
    const float* ln1s = (const float*)d_in[12];
    const float* ln1b = (const float*)d_in[13];
    const float* W1   = (const float*)d_in[14];
    const float* b1   = (const float*)d_in[15];
    const float* W2   = (const float*)d_in[16];
    const float* b2   = (const float*)d_in[17];
    const float* ln2s = (const float*)d_in[18];
    const float* ln2b = (const float*)d_in[19];
    float* out = (float*)d_out;
    u16* ws  = (u16*)d_ws;

    const long long CF = 512LL * 2048;
    const int M = B_ * T_;  // 6144

    // ws layout (u16 units). Total 51,234,816 u16 = 102.5 MB (<121.7 MB proven).
    u16* wqkvT   = ws;                      // [6][1536][512]
    u16* woT     = ws + 4718592;            // [6][512][512]
    u16* w1T     = ws + 6291456;            // [6][2048][512]
    u16* w2T     = ws + 12582912;           // [6][512][2048]
    float* bqkv  = (float*)(ws + 18874368); // [6][1536] f32
    u16* xb      = ws + 18892800;           // [M][512]
    u16* qkvb    = ws + 22038528;           // [M][1536]
    u16* vtb     = ws + 31475712;           // [64][64][768]; aliased as yb
    u16* attnb   = ws + 34621440;           // [M][512]
    u16* scr     = ws + 37767168;           // h1 [M][2048]
    float* bandg = (float*)(ws + 50350080); // [M][8][9] f32
    u16* yb      = vtb;

    const dim3 tb(32, 8);

    // --- one-time prologue ---
    transpose_qkvo<<<dim3(16, 16, 24), tb, 0, stream>>>(Wq, Wk, Wv, Wo, wqkvT, woT);
    transpose_f2bL<<<dim3(64, 16, 6), tb, 0, stream>>>(W1, 2048, CF, w1T, 512, 1048576);
    transpose_f2bL<<<dim3(16, 64, 6), tb, 0, stream>>>(W2, 512,  CF, w2T, 2048, 1048576);
    concat_bias<<<36, 256, 0, stream>>>(bq, bk, bv, bqkv);
    mask_in<<<(M * 512) / 1024, 256, 0, stream>>>(x, mask, xb);

    for (int l = 0; l < 6; ++l) {
        // QKV: [6144,512] @ [1536,512]^T; q *= log2e/8 in epilogue (cols<512)
        // -> scores & band are in exp2 domain; softmax uses bare v_exp_f32.
        gemm_bt4<3><<<dim3(96, 24), 256, 0, stream>>>(
            xb, 512, wqkvT + (long long)l * 786432, 512, bqkv + l * 1536,
            qkvb, 1536, 512, 0.125f * LOG2E);
        // bandk table for this layer
        bandg_k<<<192, 256, 0, stream>>>(qkvb, erk + l * 576, bandg);
        // V^T per head: [64][768]
        transpose_b<<<dim3(2, 24, 64), tb, 0, stream>>>(
            qkvb + 1024, 768LL * 1536, 64, 1536,
            vtb, 8LL * 64 * 768, 64LL * 768, 768);
        // fused attention -> attnb
        flash_attn<<<dim3(12, 64), 256, 0, stream>>>(
            qkvb, vtb, mask, bandg, erv + l * 576, attnb);
        // O projection -> yb (=vtb, dead now)
        gemm_bt4<0><<<dim3(96, 8), 256, 0, stream>>>(
            attnb, 512, woT + (long long)l * 262144, 512, bo + l * 512,
            yb, 512, 512, 0.f);
        add_ln<<<1536, 256, 0, stream>>>(xb, yb, ln1s + l * 512, ln1b + l * 512, xb);
        // FFN1 (relu fused)
        gemm_bt4<1><<<dim3(96, 32), 256, 0, stream>>>(
            xb, 512, w1T + (long long)l * 1048576, 512, b1 + l * 2048,
            scr, 2048, 512, 0.f);
        // FFN2
        gemm_bt4<0><<<dim3(96, 8), 256, 0, stream>>>(
            scr, 2048, w2T + (long long)l * 1048576, 2048, b2 + l * 512,
            yb, 512, 2048, 0.f);
        add_ln<<<1536, 256, 0, stream>>>(xb, yb, ln2s + l * 512, ln2b + l * 512, xb);
    }

    mask_out<<<(M * 512) / 1024, 256, 0, stream>>>(xb, mask, out);
}

// Round 9
// 1017.333 us; speedup vs baseline: 2.3601x; 1.0487x over previous
//
#include <hip/hip_runtime.h>
#include <stdint.h>

// ============================================================================
// Encoder (6-layer rel-pos transformer), MI355X. f32 in/out, bf16 internals.
// R14: R13 bugfix — K/V staging loop covered only 256 of 512 chunks with the
// new 128-thread block (rows 32-63 of Kt/Vt uninitialized -> NaN). Loop is
// now i<4. Structure otherwise identical to R13: 32 q-rows / 2 waves per
// block, single-buffered K/V, LDS ~25.5 KB -> 6 blocks/CU, grid 24x64=1536
// blocks (XCD-swizzled, bijective), exp2 domain, tree-max, native bf16 pack.
// gemm_bt4 = R10-verified body, untouched.
// ============================================================================

typedef unsigned short u16;
typedef __attribute__((ext_vector_type(8))) __bf16 bf16x8;
typedef __attribute__((ext_vector_type(4))) float f32x4;

#define B_ 8
#define T_ 768
#define C_ 512
#define F_ 2048
#define LOG2E 1.4426950408889634f

__device__ __forceinline__ float b2f(u16 u) {
    union { float f; uint32_t i; } x; x.i = ((uint32_t)u) << 16; return x.f;
}
__device__ __forceinline__ u16 f2b(float f) {
    union { float f; uint32_t i; } x; x.f = f;
    return (u16)((x.i + 0x7fffu + ((x.i >> 16) & 1u)) >> 16);  // RNE
}

// ---------------------------------------------------------------------------
// gemm_bt4 (R10-verified, DO NOT pipeline — reg-staged dbuf spills
// unconditionally here, R7+R11 evidence): 64x64 block, 4 waves, wave=32x32.
// ---------------------------------------------------------------------------
template <int EPI>
__global__ __launch_bounds__(256) void gemm_bt4(
    const u16* __restrict__ A, int aStride,
    const u16* __restrict__ Bt, int bStride,
    const float* __restrict__ bias,
    u16* __restrict__ out, int oStride, int K, float epiScale)
{
    const int tid = threadIdx.x;
    const int wave = tid >> 6, lane = tid & 63;
    const int wm = wave & 1, wn = wave >> 1;
    const int quad = lane >> 4, l16 = lane & 15;
    const int m0 = blockIdx.x * 64;
    const int n0 = blockIdx.y * 64;

    __shared__ u16 As[64 * 64];
    __shared__ u16 Bs[64 * 64];

    const f32x4 vzero = {0.f, 0.f, 0.f, 0.f};
    f32x4 acc[2][2];
#pragma unroll
    for (int i = 0; i < 2; ++i)
#pragma unroll
        for (int j = 0; j < 2; ++j) acc[i][j] = vzero;

    for (int k0 = 0; k0 < K; k0 += 64) {
#pragma unroll
        for (int i = 0; i < 2; ++i) {
            int c = tid + i * 256;
            int row = c >> 3, pc = c & 7, lc = pc ^ (row & 7);
            *(uint4*)&As[c * 8] =
                *(const uint4*)(A + (long long)(m0 + row) * aStride + (k0 + lc * 8));
            *(uint4*)&Bs[c * 8] =
                *(const uint4*)(Bt + (long long)(n0 + row) * bStride + (k0 + lc * 8));
        }
        __syncthreads();
        __builtin_amdgcn_s_setprio(1);
#pragma unroll
        for (int ks = 0; ks < 2; ++ks) {
            bf16x8 af[2], bfr[2];
#pragma unroll
            for (int mi = 0; mi < 2; ++mi) {
                int row = wm * 32 + mi * 16 + l16;
                int pc = ((ks << 2) | quad) ^ (row & 7);
                af[mi] = *(const bf16x8*)&As[row * 64 + pc * 8];
            }
#pragma unroll
            for (int ni = 0; ni < 2; ++ni) {
                int row = wn * 32 + ni * 16 + l16;
                int pc = ((ks << 2) | quad) ^ (row & 7);
                bfr[ni] = *(const bf16x8*)&Bs[row * 64 + pc * 8];
            }
#pragma unroll
            for (int mi = 0; mi < 2; ++mi)
#pragma unroll
                for (int ni = 0; ni < 2; ++ni)
                    acc[mi][ni] = __builtin_amdgcn_mfma_f32_16x16x32_bf16(
                        bfr[ni], af[mi], acc[mi][ni], 0, 0, 0);
        }
        __builtin_amdgcn_s_setprio(0);
        __syncthreads();
    }

#pragma unroll
    for (int mi = 0; mi < 2; ++mi) {
        int row = m0 + wm * 32 + mi * 16 + l16;
#pragma unroll
        for (int ni = 0; ni < 2; ++ni) {
            int colb = n0 + wn * 32 + ni * 16 + quad * 4;
            u16 pk[4];
#pragma unroll
            for (int r = 0; r < 4; ++r) {
                float v = acc[mi][ni][r] + bias[colb + r];
                if (EPI == 1) v = v > 0.f ? v : 0.f;
                if (EPI == 3) { if (colb + r < 512) v *= epiScale; }
                pk[r] = f2b(v);
            }
            uint2 p;
            p.x = (uint32_t)pk[0] | ((uint32_t)pk[1] << 16);
            p.y = (uint32_t)pk[2] | ((uint32_t)pk[3] << 16);
            *(uint2*)(out + (long long)row * oStride + colb) = p;
        }
    }
}

// ---------------------------------------------------------------------------
// bandg[(t*8 + h)*9 + e] = q~[t,h,:] . erk[e,:]  (q pre-scaled by log2e/8 —
// band lands in the same exp2 domain as the QK^T scores automatically)
// ---------------------------------------------------------------------------
__global__ __launch_bounds__(256) void bandg_k(
    const u16* __restrict__ qkv, const float* __restrict__ erk,
    float* __restrict__ bandg)
{
    __shared__ float erkS[576];
    const int tid = threadIdx.x;
    for (int idx = tid; idx < 576; idx += 256) erkS[idx] = erk[idx];
    __syncthreads();
    const int gid = blockIdx.x * 256 + tid;       // 49152
    const int row = gid >> 3, h = gid & 7;
    const u16* q = qkv + (long long)row * 1536 + h * 64;
    float acc[9];
#pragma unroll
    for (int e = 0; e < 9; ++e) acc[e] = 0.f;
#pragma unroll
    for (int c = 0; c < 8; ++c) {
        uint4 d4 = *(const uint4*)(q + c * 8);
        const uint32_t dw[4] = {d4.x, d4.y, d4.z, d4.w};
#pragma unroll
        for (int j = 0; j < 8; ++j) {
            u16 uu = (u16)((dw[j >> 1] >> ((j & 1) * 16)) & 0xffff);
            float qv = b2f(uu);
            int d = c * 8 + j;
#pragma unroll
            for (int e = 0; e < 9; ++e) acc[e] += qv * erkS[e * 64 + d];
        }
    }
    float* o = bandg + (long long)gid * 9;
#pragma unroll
    for (int e = 0; e < 9; ++e) o[e] = acc[e];
}

// ---------------------------------------------------------------------------
// Flash attention R14: 32 q-rows / 2 waves per block; single-buffered K/V;
// LDS ~25.5 KB -> 6 blocks/CU; grid 1536 blocks (XCD-swizzled). exp2 domain.
// ---------------------------------------------------------------------------
__global__ __launch_bounds__(128) void flash_attn(
    const u16* __restrict__ qkv, const u16* __restrict__ vt,
    const float* __restrict__ mask, const float* __restrict__ bandg,
    const float* __restrict__ erv, u16* __restrict__ outb)
{
    const int tid = threadIdx.x;           // 0..127
    const int w = tid >> 6, lane = tid & 63;
    const int quad = lane >> 4, l16 = lane & 15;
    // XCD swizzle: 1536 blocks, 1536 % 8 == 0 -> bijective.
    const int orig = blockIdx.y * 24 + blockIdx.x;
    const int swz = (orig & 7) * 192 + (orig >> 3);
    const int qt = swz % 24, bh = swz / 24;
    const int b = bh >> 3, h = bh & 7;
    const int q0 = qt * 32;

    __shared__ u16 Ql[32 * 64];        //  4 KB
    __shared__ u16 Kt[64 * 64];        //  8 KB
    __shared__ u16 Vt[64 * 64];        //  8 KB
    __shared__ u16 Pl[2][16 * 64];     //  4 KB
    __shared__ float bandk[32][10];    //  1.25 KB
    __shared__ float maskK[64];        //  256 B

    // Q stage: 32*64 u16 = 256 chunks / 128 threads = 2 each
#pragma unroll
    for (int i = 0; i < 2; ++i) {
        int c = tid + i * 128;
        int r = c >> 3, pc = c & 7, lc = pc ^ (r & 7);
        *(uint4*)&Ql[c * 8] =
            *(const uint4*)(qkv + (long long)(b * T_ + q0 + r) * 1536 + h * 64 + lc * 8);
    }
    for (int idx = tid; idx < 288; idx += 128) {
        int r = idx / 9, e = idx - r * 9;
        bandk[r][e] = bandg[((long long)(b * T_ + q0 + r) * 8 + h) * 9 + e];
    }

    const int i_row = q0 + w * 16 + l16;
    const float mi = mask[b * T_ + i_row];
    float m_run = -1e30f, l_run = 0.f;
    const f32x4 vzero = {0.f, 0.f, 0.f, 0.f};
    f32x4 vacc[4] = {vzero, vzero, vzero, vzero};
    float pb[3] = {0.f, 0.f, 0.f};

    __syncthreads();
    bf16x8 qf[2];
#pragma unroll
    for (int ks = 0; ks < 2; ++ks) {
        int r = w * 16 + l16;
        int pc = ((ks << 2) | quad) ^ (r & 7);
        qf[ks] = *(const bf16x8*)&Ql[r * 64 + pc * 8];
    }

    for (int kt = 0; kt < 12; ++kt) {
        __syncthreads();   // all waves done reading Kt/Vt from previous iter
        // K/V stage: 64*64 u16 = 512 chunks each / 128 threads = 4 each
        // (R13 bug: i<2 left rows 32-63 uninitialized -> NaN)
#pragma unroll
        for (int i = 0; i < 4; ++i) {
            int c = tid + i * 128;
            int r = c >> 3, pc = c & 7, lc = pc ^ (r & 7);
            *(uint4*)&Kt[c * 8] =
                *(const uint4*)(qkv + (long long)(b * T_ + kt * 64 + r) * 1536 + 512 + h * 64 + lc * 8);
            *(uint4*)&Vt[c * 8] =
                *(const uint4*)(vt + ((long long)bh * 64 + r) * T_ + kt * 64 + lc * 8);
        }
        if (tid < 64) maskK[tid] = mask[b * T_ + kt * 64 + tid];
        __syncthreads();

        const float mkv = maskK[lane];
        const bool tile_clean = (__ballot(mkv == 0.f) == 0ull);
        const bool fast = tile_clean && (mi != 0.f);
        const bool has_band = (kt * 64 <= q0 + w * 16 + 19) &&
                              (kt * 64 + 67 >= q0 + w * 16);

        f32x4 sacc[4];
#pragma unroll
        for (int ni = 0; ni < 4; ++ni) sacc[ni] = vzero;
        __builtin_amdgcn_s_setprio(1);
#pragma unroll
        for (int ks = 0; ks < 2; ++ks)
#pragma unroll
            for (int ni = 0; ni < 4; ++ni) {
                int r = ni * 16 + l16;
                int pc = ((ks << 2) | quad) ^ (r & 7);
                bf16x8 kf = *(const bf16x8*)&Kt[r * 64 + pc * 8];
                sacc[ni] = __builtin_amdgcn_mfma_f32_16x16x32_bf16(kf, qf[ks], sacc[ni], 0, 0, 0);
            }
        __builtin_amdgcn_s_setprio(0);

        if (has_band) {
#pragma unroll
            for (int ni = 0; ni < 4; ++ni)
#pragma unroll
                for (int r = 0; r < 4; ++r) {
                    int jl = ni * 16 + quad * 4 + r;
                    int dlt = kt * 64 + jl - i_row;
                    if (dlt >= -4 && dlt <= 4)
                        sacc[ni][r] += bandk[w * 16 + l16][dlt + 4];
                }
        }
        if (!fast) {
#pragma unroll
            for (int ni = 0; ni < 4; ++ni)
#pragma unroll
                for (int r = 0; r < 4; ++r) {
                    int jl = ni * 16 + quad * 4 + r;
                    if (mi * maskK[jl] == 0.f) sacc[ni][r] = -14427.0f;  // -10000*log2e
                }
        }

        // row max: pairwise tree
        float mx;
        {
            float a0 = fmaxf(sacc[0][0], sacc[0][1]), a1 = fmaxf(sacc[0][2], sacc[0][3]);
            float b0 = fmaxf(sacc[1][0], sacc[1][1]), b1 = fmaxf(sacc[1][2], sacc[1][3]);
            float c0 = fmaxf(sacc[2][0], sacc[2][1]), c1 = fmaxf(sacc[2][2], sacc[2][3]);
            float d0 = fmaxf(sacc[3][0], sacc[3][1]), d1 = fmaxf(sacc[3][2], sacc[3][3]);
            float t0 = fmaxf(fmaxf(a0, a1), fmaxf(b0, b1));
            float t1 = fmaxf(fmaxf(c0, c1), fmaxf(d0, d1));
            mx = fmaxf(t0, t1);
        }
        mx = fmaxf(mx, __shfl_xor(mx, 16));
        mx = fmaxf(mx, __shfl_xor(mx, 32));
        const float m_new = fmaxf(m_run, mx);
        const float alpha = exp2f(m_run - m_new);
        m_run = m_new;
        l_run *= alpha;
#pragma unroll
        for (int ni = 0; ni < 4; ++ni) vacc[ni] = vacc[ni] * alpha;
#pragma unroll
        for (int k = 0; k < 3; ++k) pb[k] *= alpha;

        // exp2 + native-pack P tile
        float lsum = 0.f;
#pragma unroll
        for (int ni = 0; ni < 4; ++ni) {
            float u0 = exp2f(sacc[ni][0] - m_new);
            float u1 = exp2f(sacc[ni][1] - m_new);
            float u2 = exp2f(sacc[ni][2] - m_new);
            float u3 = exp2f(sacc[ni][3] - m_new);
            lsum += (u0 + u1) + (u2 + u3);
            union { __bf16 h[2]; uint32_t u; } cA, cB;
            cA.h[0] = (__bf16)u0; cA.h[1] = (__bf16)u1;
            cB.h[0] = (__bf16)u2; cB.h[1] = (__bf16)u3;
            int c0 = ni * 16 + quad * 4;
            int phys = (((c0 >> 3) ^ (l16 & 7)) << 3) + (c0 & 7);
            uint2 p; p.x = cA.u; p.y = cB.u;
            *(uint2*)&Pl[w][l16 * 64 + phys] = p;
        }
        l_run += lsum;

        if (has_band) {
#pragma unroll
            for (int k = 0; k < 3; ++k) {
                int e = quad * 3 + k;
                if (e < 9) {
                    int jl = i_row + e - 4 - kt * 64;
                    if (jl >= 0 && jl < 64) {
                        int phys = (((jl >> 3) ^ (l16 & 7)) << 3) + (jl & 7);
                        pb[k] += b2f(Pl[w][l16 * 64 + phys]);
                    }
                }
            }
        }

        __builtin_amdgcn_s_setprio(1);
#pragma unroll
        for (int ks = 0; ks < 2; ++ks) {
            int pcc = ((ks << 2) | quad) ^ (l16 & 7);
            bf16x8 pf = *(const bf16x8*)&Pl[w][l16 * 64 + pcc * 8];
#pragma unroll
            for (int ni = 0; ni < 4; ++ni) {
                int r = ni * 16 + l16;
                int pc = ((ks << 2) | quad) ^ (r & 7);
                bf16x8 vf = *(const bf16x8*)&Vt[r * 64 + pc * 8];
                vacc[ni] = __builtin_amdgcn_mfma_f32_16x16x32_bf16(vf, pf, vacc[ni], 0, 0, 0);
            }
        }
        __builtin_amdgcn_s_setprio(0);
    }

    l_run += __shfl_xor(l_run, 16);
    l_run += __shfl_xor(l_run, 32);
    const float rinv = 1.f / l_run;

    float pband[9];
#pragma unroll
    for (int e = 0; e < 9; ++e) {
        float val = (quad == e / 3) ? pb[e % 3] : 0.f;
        val += __shfl_xor(val, 16);
        val += __shfl_xor(val, 32);
        pband[e] = val * rinv;
    }

    u16* orow = outb + (long long)(b * T_ + i_row) * C_ + h * 64;
#pragma unroll
    for (int ni = 0; ni < 4; ++ni) {
        u16 pk[4];
#pragma unroll
        for (int r = 0; r < 4; ++r) {
            int d = ni * 16 + quad * 4 + r;
            float v = vacc[ni][r] * rinv;
#pragma unroll
            for (int e = 0; e < 9; ++e) v += pband[e] * erv[e * 64 + d];
            pk[r] = f2b(v);
        }
        uint2 p;
        p.x = (uint32_t)pk[0] | ((uint32_t)pk[1] << 16);
        p.y = (uint32_t)pk[2] | ((uint32_t)pk[3] << 16);
        *(uint2*)(orow + ni * 16 + quad * 4) = p;
    }
}

// ---------------------------------------------------------------------------
// One-time weight transposes (f32 -> bf16), batched over layers.
// ---------------------------------------------------------------------------
__global__ void transpose_qkvo(const float* __restrict__ Wq, const float* __restrict__ Wk,
                               const float* __restrict__ Wv, const float* __restrict__ Wo,
                               u16* __restrict__ wqkvT, u16* __restrict__ woT)
{
    __shared__ u16 tile[32][33];
    const int z = blockIdx.z, l = z >> 2, which = z & 3;
    const float* src = (which == 0 ? Wq : which == 1 ? Wk : which == 2 ? Wv : Wo)
                       + (long long)l * 262144;
    u16* dst = (which == 3) ? woT + (long long)l * 262144
                            : wqkvT + (long long)l * 786432 + which * 262144;
    const int r0 = blockIdx.y * 32, c0 = blockIdx.x * 32;
    const int tx = threadIdx.x, ty = threadIdx.y;
#pragma unroll
    for (int i = 0; i < 32; i += 8)
        tile[ty + i][tx] = f2b(src[(long long)(r0 + ty + i) * 512 + (c0 + tx)]);
    __syncthreads();
#pragma unroll
    for (int i = 0; i < 32; i += 8)
        dst[(long long)(c0 + ty + i) * 512 + (r0 + tx)] = tile[tx][ty + i];
}

__global__ void transpose_f2bL(const float* __restrict__ src0, int sStride, long long sLayer,
                               u16* __restrict__ dst0, int dStride, long long dLayer)
{
    __shared__ u16 tile[32][33];
    const int l = blockIdx.z;
    const float* src = src0 + (long long)l * sLayer;
    u16* dst = dst0 + (long long)l * dLayer;
    const int r0 = blockIdx.y * 32, c0 = blockIdx.x * 32;
    const int tx = threadIdx.x, ty = threadIdx.y;
#pragma unroll
    for (int i = 0; i < 32; i += 8)
        tile[ty + i][tx] = f2b(src[(long long)(r0 + ty + i) * sStride + (c0 + tx)]);
    __syncthreads();
#pragma unroll
    for (int i = 0; i < 32; i += 8)
        dst[(long long)(c0 + ty + i) * dStride + (r0 + tx)] = tile[tx][ty + i];
}

__global__ void transpose_b(const u16* __restrict__ src, long long sB1, long long sB2, int sStride,
                            u16* __restrict__ dst, long long dB1, long long dB2, int dStride)
{
    __shared__ u16 tile[32][33];
    const int z = blockIdx.z, zb = z >> 3, zh = z & 7;
    src += (long long)zb * sB1 + (long long)zh * sB2;
    dst += (long long)zb * dB1 + (long long)zh * dB2;
    const int r0 = blockIdx.y * 32, c0 = blockIdx.x * 32;
    const int tx = threadIdx.x, ty = threadIdx.y;
#pragma unroll
    for (int i = 0; i < 32; i += 8)
        tile[ty + i][tx] = src[(long long)(r0 + ty + i) * sStride + (c0 + tx)];
    __syncthreads();
#pragma unroll
    for (int i = 0; i < 32; i += 8)
        dst[(long long)(c0 + ty + i) * dStride + (r0 + tx)] = tile[tx][ty + i];
}

__global__ void concat_bias(const float* __restrict__ bq, const float* __restrict__ bk,
                            const float* __restrict__ bv, float* __restrict__ dst)
{
    int i = blockIdx.x * 256 + threadIdx.x;
    int l = i / 1536, n = i - l * 1536;
    float v = (n < 512) ? bq[l * 512 + n]
             : (n < 1024 ? bk[l * 512 + (n - 512)] : bv[l * 512 + (n - 1024)]);
    dst[i] = v;
}

__global__ void mask_in(const float* __restrict__ x, const float* __restrict__ mask,
                        u16* __restrict__ out)
{
    int i4 = (blockIdx.x * 256 + threadIdx.x) * 4;
    float4 xv = *(const float4*)(x + i4);
    float m = mask[i4 >> 9];
    u16 pk[4] = {f2b(xv.x * m), f2b(xv.y * m), f2b(xv.z * m), f2b(xv.w * m)};
    uint2 p; p.x = (uint32_t)pk[0] | ((uint32_t)pk[1] << 16);
    p.y = (uint32_t)pk[2] | ((uint32_t)pk[3] << 16);
    *(uint2*)(out + i4) = p;
}

__global__ void mask_out(const u16* __restrict__ x, const float* __restrict__ mask,
                         float* __restrict__ out)
{
    int i4 = (blockIdx.x * 256 + threadIdx.x) * 4;
    uint2 p = *(const uint2*)(x + i4);
    float m = mask[i4 >> 9];
    float4 o;
    o.x = b2f((u16)(p.x & 0xffff)) * m;
    o.y = b2f((u16)(p.x >> 16)) * m;
    o.z = b2f((u16)(p.y & 0xffff)) * m;
    o.w = b2f((u16)(p.y >> 16)) * m;
    *(float4*)(out + i4) = o;
}

__global__ __launch_bounds__(256) void add_ln(
    const u16* __restrict__ x, const u16* __restrict__ y,
    const float* __restrict__ sc, const float* __restrict__ bi,
    u16* __restrict__ outx)
{
    const int wave = threadIdx.x >> 6, lane = threadIdx.x & 63;
    const long long r = (long long)blockIdx.x * 4 + wave;
    const u16* xr = x + r * C_;
    const u16* yr = y + r * C_;
    float v[8], s = 0.f;
#pragma unroll
    for (int it = 0; it < 2; ++it) {
        int j0 = it * 256 + lane * 4;
        uint2 px = *(const uint2*)(xr + j0);
        uint2 py = *(const uint2*)(yr + j0);
        v[it * 4 + 0] = b2f((u16)(px.x & 0xffff)) + b2f((u16)(py.x & 0xffff));
        v[it * 4 + 1] = b2f((u16)(px.x >> 16))    + b2f((u16)(py.x >> 16));
        v[it * 4 + 2] = b2f((u16)(px.y & 0xffff)) + b2f((u16)(py.y & 0xffff));
        v[it * 4 + 3] = b2f((u16)(px.y >> 16))    + b2f((u16)(py.y >> 16));
        s += v[it * 4 + 0] + v[it * 4 + 1] + v[it * 4 + 2] + v[it * 4 + 3];
    }
#pragma unroll
    for (int off = 32; off > 0; off >>= 1) s += __shfl_down(s, off);
    s = __shfl(s, 0);
    const float mean = s * (1.f / 512.f);
    float var = 0.f;
#pragma unroll
    for (int l = 0; l < 8; ++l) { float d = v[l] - mean; var += d * d; }
#pragma unroll
    for (int off = 32; off > 0; off >>= 1) var += __shfl_down(var, off);
    var = __shfl(var, 0);
    const float rs = rsqrtf(var * (1.f / 512.f) + 1e-6f);
    u16* orow = outx + r * C_;
#pragma unroll
    for (int it = 0; it < 2; ++it) {
        int j0 = it * 256 + lane * 4;
        float4 s4 = *(const float4*)(sc + j0);
        float4 b4 = *(const float4*)(bi + j0);
        u16 pk[4];
        pk[0] = f2b((v[it * 4 + 0] - mean) * rs * s4.x + b4.x);
        pk[1] = f2b((v[it * 4 + 1] - mean) * rs * s4.y + b4.y);
        pk[2] = f2b((v[it * 4 + 2] - mean) * rs * s4.z + b4.z);
        pk[3] = f2b((v[it * 4 + 3] - mean) * rs * s4.w + b4.w);
        uint2 p; p.x = (uint32_t)pk[0] | ((uint32_t)pk[1] << 16);
        p.y = (uint32_t)pk[2] | ((uint32_t)pk[3] << 16);
        *(uint2*)(orow + j0) = p;
    }
}

// ===========================================================================
extern "C" void kernel_launch(void* const* d_in, const int* in_sizes, int n_in,
                              void* d_out, int out_size, void* d_ws, size_t ws_size,
                              hipStream_t stream)
{
    const float* x    = (const float*)d_in[0];
    const float* mask = (const float*)d_in[1];
    const float* Wq   = (const float*)d_in[2];
    const float* bq   = (const float*)d_in[3];
    const float* Wk   = (const float*)d_in[4];
    const float* bk   = (const float*)d_in[5];
    const float* Wv   = (const float*)d_in[6];
    const float* bv   = (const float*)d_in[7];
    const float* Wo   = (const float*)d_in[8];
    const float* bo   = (const float*)d_in[9];
    const float* erk  = (const float*)d_in[10];
    const float* erv  = (const float*)d_in[11];
    const float* ln1s = (const float*)d_in[12];
    const float* ln1b = (const float*)d_in[13];
    const float* W1   = (const float*)d_in[14];
    const float* b1   = (const float*)d_in[15];
    const float* W2   = (const float*)d_in[16];
    const float* b2   = (const float*)d_in[17];
    const float* ln2s = (const float*)d_in[18];
    const float* ln2b = (const float*)d_in[19];
    float* out = (float*)d_out;
    u16* ws  = (u16*)d_ws;

    const long long CF = 512LL * 2048;
    const int M = B_ * T_;  // 6144

    // ws layout (u16 units). Total 51,234,816 u16 = 102.5 MB (<121.7 MB proven).
    u16* wqkvT   = ws;                      // [6][1536][512]
    u16* woT     = ws + 4718592;            // [6][512][512]
    u16* w1T     = ws + 6291456;            // [6][2048][512]
    u16* w2T     = ws + 12582912;           // [6][512][2048]
    float* bqkv  = (float*)(ws + 18874368); // [6][1536] f32
    u16* xb      = ws + 18892800;           // [M][512]
    u16* qkvb    = ws + 22038528;           // [M][1536]
    u16* vtb     = ws + 31475712;           // [64][64][768]; aliased as yb
    u16* attnb   = ws + 34621440;           // [M][512]
    u16* scr     = ws + 37767168;           // h1 [M][2048]
    float* bandg = (float*)(ws + 50350080); // [M][8][9] f32
    u16* yb      = vtb;

    const dim3 tb(32, 8);

    // --- one-time prologue ---
    transpose_qkvo<<<dim3(16, 16, 24), tb, 0, stream>>>(Wq, Wk, Wv, Wo, wqkvT, woT);
    transpose_f2bL<<<dim3(64, 16, 6), tb, 0, stream>>>(W1, 2048, CF, w1T, 512, 1048576);
    transpose_f2bL<<<dim3(16, 64, 6), tb, 0, stream>>>(W2, 512,  CF, w2T, 2048, 1048576);
    concat_bias<<<36, 256, 0, stream>>>(bq, bk, bv, bqkv);
    mask_in<<<(M * 512) / 1024, 256, 0, stream>>>(x, mask, xb);

    for (int l = 0; l < 6; ++l) {
        // QKV: [6144,512] @ [1536,512]^T; q *= log2e/8 in epilogue (cols<512)
        gemm_bt4<3><<<dim3(96, 24), 256, 0, stream>>>(
            xb, 512, wqkvT + (long long)l * 786432, 512, bqkv + l * 1536,
            qkvb, 1536, 512, 0.125f * LOG2E);
        // bandk table for this layer
        bandg_k<<<192, 256, 0, stream>>>(qkvb, erk + l * 576, bandg);
        // V^T per head: [64][768]
        transpose_b<<<dim3(2, 24, 64), tb, 0, stream>>>(
            qkvb + 1024, 768LL * 1536, 64, 1536,
            vtb, 8LL * 64 * 768, 64LL * 768, 768);
        // fused attention -> attnb (1536 blocks x 2 waves)
        flash_attn<<<dim3(24, 64), 128, 0, stream>>>(
            qkvb, vtb, mask, bandg, erv + l * 576, attnb);
        // O projection -> yb (=vtb, dead now)
        gemm_bt4<0><<<dim3(96, 8), 256, 0, stream>>>(
            attnb, 512, woT + (long long)l * 262144, 512, bo + l * 512,
            yb, 512, 512, 0.f);
        add_ln<<<1536, 256, 0, stream>>>(xb, yb, ln1s + l * 512, ln1b + l * 512, xb);
        // FFN1 (relu fused)
        gemm_bt4<1><<<dim3(96, 32), 256, 0, stream>>>(
            xb, 512, w1T + (long long)l * 1048576, 512, b1 + l * 2048,
            scr, 2048, 512, 0.f);
        // FFN2
        gemm_bt4<0><<<dim3(96, 8), 256, 0, stream>>>(
            scr, 2048, w2T + (long long)l * 1048576, 2048, b2 + l * 512,
            yb, 512, 2048, 0.f);
        add_ln<<<1536, 256, 0, stream>>>(xb, yb, ln2s + l * 512, ln2b + l * 512, xb);
    }

    mask_out<<<(M * 512) / 1024, 256, 0, stream>>>(xb, mask, out);
}